// Round 10
// baseline (2583.297 us; speedup 1.0000x reference)
//
#include <hip/hip_runtime.h>
#include <hip/hip_bf16.h>

#define NL 6
#define DT 6144
#define DM 768
#define TOK 128

// encode geometry (r7 chassis)
#define EFT 48            // f-tile (3 waves x 16)
#define EBK 128           // k-step (f32 cols per staged tile)
#define EREP 24           // MEASUREMENT: repeat encode body (idempotent)

// decode geometry: r9 (in-block i-accumulation, per-j f-split)
#define TD 256
#define NTD 3

using bf16x8 = __attribute__((ext_vector_type(8))) short;
using f32x4  = __attribute__((ext_vector_type(4))) float;

typedef unsigned int u32;
typedef __attribute__((address_space(1))) const u32 gu32;
typedef __attribute__((address_space(3))) u32 lu32;

// async global->LDS, 16B per lane; LDS dest = wave-uniform base + lane*16
__device__ __forceinline__ void stage16(const float* g, float* l) {
  __builtin_amdgcn_global_load_lds((gu32*)g, (lu32*)l, 16, 0, 0);
}

// round-to-nearest-even f32 -> bf16 (branchless; inputs are finite)
__device__ __forceinline__ short f2bf(float f) {
  union { float f; unsigned u; } c; c.f = f;
  unsigned u = c.u;
  u += 0x7fffu + ((u >> 16) & 1u);
  return (short)(u >> 16);
}

__device__ __forceinline__ bf16x8 cvt8(float4 v0, float4 v1) {
  bf16x8 r;
  r[0] = f2bf(v0.x); r[1] = f2bf(v0.y); r[2] = f2bf(v0.z); r[3] = f2bf(v0.w);
  r[4] = f2bf(v1.x); r[5] = f2bf(v1.y); r[6] = f2bf(v1.z); r[7] = f2bf(v1.w);
  return r;
}

// acts[l][n][f] = relu(x[l] @ W_enc[l]^T + b_enc[l]), bf16 output.
// r7 chassis; MEASUREMENT ROUND: body repeated EREP times (idempotent).
__global__ __launch_bounds__(192, 2) void encode_k(
    const float* __restrict__ x, const float* __restrict__ W_enc,
    const float* __restrict__ b_enc, ushort* __restrict__ acts)
{
  __shared__ float lw[2][EFT][EBK];   // 2 x 24 KB

  const int l  = blockIdx.x / (DT / EFT);
  const int f0 = (blockIdx.x % (DT / EFT)) * EFT;
  const int w    = threadIdx.x >> 6;        // 0..2
  const int lane = threadIdx.x & 63;
  const int lo = lane & 15, hi = lane >> 4;

  const float* We = W_enc + ((size_t)l * DT + f0) * DM;
  const float* xl = x + (size_t)l * TOK * DM;

  const int sub = lane >> 5;   // 0..1 (staging row within pair)
  const int ch  = lane & 31;   // staging 16B chunk

  #pragma unroll 1
  for (int rep = 0; rep < EREP; ++rep) {
    f32x4 acc[8];
    #pragma unroll
    for (int mi = 0; mi < 8; ++mi) acc[mi] = f32x4{0.f, 0.f, 0.f, 0.f};

    // stage step 0 (swizzled source, linear dest)
    #pragma unroll
    for (int q = 0; q < 8; ++q) {
      const int row = w * 16 + q * 2 + sub;
      const int g   = ch ^ (row & 7);
      stage16(We + (size_t)row * DM + g * 4, &lw[0][w * 16 + q * 2][0]);
    }
    __syncthreads();

    int cur = 0;
    #pragma unroll 1
    for (int st = 0; st < DM / EBK; ++st) {
      if (st + 1 < DM / EBK) {
        #pragma unroll
        for (int q = 0; q < 8; ++q) {
          const int row = w * 16 + q * 2 + sub;
          const int g   = ch ^ (row & 7);
          stage16(We + (size_t)row * DM + (st + 1) * EBK + g * 4,
                  &lw[cur ^ 1][w * 16 + q * 2][0]);
        }
      }

      const int rr_ = w * 16 + lo;                 // read row; (rr_&7)==(lo&7)
      #pragma unroll
      for (int ks = 0; ks < 4; ++ks) {
        bf16x8 a[8];
        #pragma unroll
        for (int mi = 0; mi < 8; ++mi) {
          const float* p = xl + (size_t)(mi * 16 + lo) * DM + st * EBK + ks * 32 + hi * 8;
          a[mi] = cvt8(*(const float4*)p, *(const float4*)(p + 4));
        }

        const int c0 = ks * 8 + ((hi * 2) ^ (lo & 7));
        const int c1 = ks * 8 + ((hi * 2 + 1) ^ (lo & 7));
        const float4 b0 = *(const float4*)&lw[cur][rr_][c0 * 4];
        const float4 b1 = *(const float4*)&lw[cur][rr_][c1 * 4];
        bf16x8 bb;
        bb[0] = f2bf(b0.x); bb[1] = f2bf(b0.y); bb[2] = f2bf(b0.z); bb[3] = f2bf(b0.w);
        bb[4] = f2bf(b1.x); bb[5] = f2bf(b1.y); bb[6] = f2bf(b1.z); bb[7] = f2bf(b1.w);

        #pragma unroll
        for (int mi = 0; mi < 8; ++mi)
          acc[mi] = __builtin_amdgcn_mfma_f32_16x16x32_bf16(a[mi], bb, acc[mi], 0, 0, 0);
      }

      __syncthreads();
      cur ^= 1;
    }

    const int f = f0 + w * 16 + lo;
    const float bias = b_enc[l * DT + f];
    #pragma unroll
    for (int mi = 0; mi < 8; ++mi) {
      #pragma unroll
      for (int rr = 0; rr < 4; ++rr) {
        const int n = mi * 16 + hi * 4 + rr;
        float v = acc[mi][rr] + bias;
        v = v > 0.f ? v : 0.f;
        acts[((size_t)l * TOK + n) * DT + f] = (ushort)f2bf(v);
      }
    }
    __syncthreads();
  }
}

// decode grid tables: per j, S_j f-splits of width F_j, x NTD d-tiles.
__device__ const int SJ_[6]   = {6, 12, 16, 24, 24, 32};
__device__ const int FJ_[6]   = {1024, 512, 384, 256, 256, 192};
__device__ const int BOFF_[7] = {0, 18, 54, 102, 174, 246, 342};

// out[j][n][d] = b_dec[j][d] (added by sp==0 block) + sum_{i<=j} acts[i] @ W_dec[i][j]
__global__ __launch_bounds__(256, 2) void decode_k(
    const ushort* __restrict__ acts, const float* __restrict__ W_dec,
    const float* __restrict__ b_dec, float* __restrict__ out)
{
  __shared__ float lw[2][32][TD];   // 64 KB

  const int bid = blockIdx.x;
  int j = 0;
  #pragma unroll
  for (int jj = 1; jj < 6; ++jj) if (bid >= BOFF_[jj]) j = jj;
  const int r  = bid - BOFF_[j];
  const int S  = SJ_[j];
  const int F  = FJ_[j];
  const int t  = r / S;
  const int sp = r % S;
  const int fb = sp * F;
  const int ns = F / 32;            // k-steps per i
  const int nv = (j + 1) * ns;      // total virtual steps

  const int w = threadIdx.x >> 6;
  const int lane = threadIdx.x & 63;
  const int lo = lane & 15, hi = lane >> 4;

  f32x4 acc[8][4];
  #pragma unroll
  for (int mi = 0; mi < 8; ++mi)
    #pragma unroll
    for (int ni = 0; ni < 4; ++ni)
      acc[mi][ni] = f32x4{0.f, 0.f, 0.f, 0.f};

  {
    const float* W0 = W_dec + ((size_t)(0 * NL + j) * DT + fb) * DM + t * TD;
    #pragma unroll
    for (int q = 0; q < 8; ++q) {
      const int row = w * 8 + q;
      stage16(W0 + (size_t)row * DM + lane * 4, &lw[0][row][0]);
    }
  }
  __syncthreads();

  int cur = 0;
  int i = 0, s = 0;
  #pragma unroll 1
  for (int v = 0; v < nv; ++v) {
    int i2 = i, s2 = s + 1;
    if (s2 == ns) { s2 = 0; ++i2; }

    if (v + 1 < nv) {
      const float* Ws = W_dec + ((size_t)(i2 * NL + j) * DT + fb + s2 * 32) * DM + t * TD;
      #pragma unroll
      for (int q = 0; q < 8; ++q) {
        const int row = w * 8 + q;
        stage16(Ws + (size_t)row * DM + lane * 4, &lw[cur ^ 1][row][0]);
      }
    }

    const ushort* Av = acts + (size_t)i * TOK * DT + fb + s * 32;
    bf16x8 a[8];
    #pragma unroll
    for (int mi = 0; mi < 8; ++mi)
      a[mi] = *(const bf16x8*)(Av + (size_t)(mi * 16 + lo) * DT + hi * 8);

    bf16x8 bb[4];
    #pragma unroll
    for (int ni = 0; ni < 4; ++ni) {
      const int col = w * 64 + ni * 16 + lo;
      #pragma unroll
      for (int e = 0; e < 8; ++e)
        bb[ni][e] = f2bf(lw[cur][hi * 8 + e][col]);
    }

    #pragma unroll
    for (int mi = 0; mi < 8; ++mi)
      #pragma unroll
      for (int ni = 0; ni < 4; ++ni)
        acc[mi][ni] = __builtin_amdgcn_mfma_f32_16x16x32_bf16(a[mi], bb[ni], acc[mi][ni], 0, 0, 0);

    __syncthreads();
    cur ^= 1;
    i = i2; s = s2;
  }

  float* oj = out + (size_t)j * TOK * DM;
  #pragma unroll
  for (int ni = 0; ni < 4; ++ni) {
    const int d = t * TD + w * 64 + ni * 16 + lo;
    const float bias = (sp == 0) ? b_dec[j * DM + d] : 0.f;
    #pragma unroll
    for (int mi = 0; mi < 8; ++mi)
      #pragma unroll
      for (int rr = 0; rr < 4; ++rr)
        atomicAdd(oj + (size_t)(mi * 16 + hi * 4 + rr) * DM + d, acc[mi][ni][rr] + bias);
  }
}

extern "C" void kernel_launch(void* const* d_in, const int* in_sizes, int n_in,
                              void* d_out, int out_size, void* d_ws, size_t ws_size,
                              hipStream_t stream) {
  const float* x     = (const float*)d_in[0];
  const float* W_enc = (const float*)d_in[1];
  const float* b_enc = (const float*)d_in[2];
  const float* b_dec = (const float*)d_in[3];
  const float* W_dec = (const float*)d_in[4];
  float* out = (float*)d_out;
  ushort* acts = (ushort*)d_ws;   // 6*128*6144 bf16 = 9.44 MB

  hipMemsetAsync(out, 0, (size_t)out_size * sizeof(float), stream);
  encode_k<<<dim3(NL * (DT / EFT)), dim3(192), 0, stream>>>(x, W_enc, b_enc, acts);
  decode_k<<<dim3(342), dim3(256), 0, stream>>>(acts, W_dec, b_dec, out);
}

// Round 11
// 199.023 us; speedup vs baseline: 12.9799x; 12.9799x over previous
//
#include <hip/hip_runtime.h>
#include <hip/hip_bf16.h>

#define NL 6
#define DT 6144
#define DM 768
#define TOK 128

// encode: decode-clone staging. Tile C=[128 tok][EF f], staged W chunk [EF][EK]
#define EF 32             // f-rows per block (4 waves x 8 rows staged)
#define EK 256            // k-cols per step (1 KB/row -> contiguous stage16)
#define ENST (DM / EK)    // 3 k-steps

// decode geometry: r9 (in-block i-accumulation, per-j f-split) -- proven
#define TD 256
#define NTD 3

using bf16x8 = __attribute__((ext_vector_type(8))) short;
using f32x4  = __attribute__((ext_vector_type(4))) float;

typedef unsigned int u32;
typedef __attribute__((address_space(1))) const u32 gu32;
typedef __attribute__((address_space(3))) u32 lu32;

// async global->LDS, 16B per lane; LDS dest = wave-uniform base + lane*16.
// RULE (r10 finding): each instruction's 64 lane addresses MUST form one
// contiguous aligned 1KB block, or DMA throughput collapses ~10x.
__device__ __forceinline__ void stage16(const float* g, float* l) {
  __builtin_amdgcn_global_load_lds((gu32*)g, (lu32*)l, 16, 0, 0);
}

// round-to-nearest-even f32 -> bf16 (branchless; inputs are finite)
__device__ __forceinline__ short f2bf(float f) {
  union { float f; unsigned u; } c; c.f = f;
  unsigned u = c.u;
  u += 0x7fffu + ((u >> 16) & 1u);
  return (short)(u >> 16);
}

// xb = bf16(x)
__global__ void initcvt_k(const float* __restrict__ x, ushort* __restrict__ xb) {
  int idx = blockIdx.x * 256 + threadIdx.x;
  if (idx < NL * TOK * DM) xb[idx] = (ushort)f2bf(x[idx]);
}

// acts[l][n][f] = relu(x[l] @ W_enc[l]^T + b_enc[l]), bf16 out.
// Decode-clone: per step stage [EF=32 f-rows][EK=256 k] f32 = 32 KB via
// 8 stage16/wave, each = one row's contiguous 1KB segment. A = xb (bf16,
// L2-hot, dwordx4). B = scalar LDS f32 + cvt. 2 blocks/CU (128 KB LDS).
// grid: 6 * 192 = 1152 blocks; 256 thr; wave w owns tok rows [w*32, w*32+32).
__global__ __launch_bounds__(256, 2) void encode_k(
    const ushort* __restrict__ xb, const float* __restrict__ W_enc,
    const float* __restrict__ b_enc, ushort* __restrict__ acts)
{
  __shared__ float lw[2][EF][EK];   // 2 x 32 KB

  const int l  = blockIdx.x / (DT / EF);
  const int f0 = (blockIdx.x % (DT / EF)) * EF;
  const int w    = threadIdx.x >> 6;        // 0..3
  const int lane = threadIdx.x & 63;
  const int lo = lane & 15, hi = lane >> 4;

  const float*  We = W_enc + ((size_t)l * DT + f0) * DM;
  const ushort* Xb = xb + (size_t)l * TOK * DM;

  f32x4 acc[2][2];
  #pragma unroll
  for (int mi = 0; mi < 2; ++mi)
    #pragma unroll
    for (int ni = 0; ni < 2; ++ni)
      acc[mi][ni] = f32x4{0.f, 0.f, 0.f, 0.f};

  // stage step 0: wave w stages rows w*8..w*8+7, one contiguous 1KB per instr
  #pragma unroll
  for (int q = 0; q < 8; ++q) {
    const int row = w * 8 + q;
    stage16(We + (size_t)row * DM + lane * 4, &lw[0][row][0]);
  }
  __syncthreads();

  int cur = 0;
  #pragma unroll 1
  for (int st = 0; st < ENST; ++st) {
    if (st + 1 < ENST) {
      #pragma unroll
      for (int q = 0; q < 8; ++q) {
        const int row = w * 8 + q;
        stage16(We + (size_t)row * DM + (st + 1) * EK + lane * 4,
                &lw[cur ^ 1][row][0]);
      }
    }

    #pragma unroll
    for (int ks = 0; ks < EK / 32; ++ks) {
      bf16x8 a[2], b[2];
      #pragma unroll
      for (int mi = 0; mi < 2; ++mi)
        a[mi] = *(const bf16x8*)(Xb + (size_t)(w * 32 + mi * 16 + lo) * DM
                                 + st * EK + ks * 32 + hi * 8);
      #pragma unroll
      for (int ni = 0; ni < 2; ++ni)
        #pragma unroll
        for (int e = 0; e < 8; ++e)
          b[ni][e] = f2bf(lw[cur][ni * 16 + lo][ks * 32 + hi * 8 + e]);

      #pragma unroll
      for (int mi = 0; mi < 2; ++mi)
        #pragma unroll
        for (int ni = 0; ni < 2; ++ni)
          acc[mi][ni] = __builtin_amdgcn_mfma_f32_16x16x32_bf16(a[mi], b[ni], acc[mi][ni], 0, 0, 0);
    }

    __syncthreads();
    cur ^= 1;
  }

  #pragma unroll
  for (int ni = 0; ni < 2; ++ni) {
    const int f = f0 + ni * 16 + lo;
    const float bias = b_enc[l * DT + f];
    #pragma unroll
    for (int mi = 0; mi < 2; ++mi) {
      #pragma unroll
      for (int rr = 0; rr < 4; ++rr) {
        const int n = w * 32 + mi * 16 + hi * 4 + rr;
        float v = acc[mi][ni][rr] + bias;
        v = v > 0.f ? v : 0.f;
        acts[((size_t)l * TOK + n) * DT + f] = (ushort)f2bf(v);
      }
    }
  }
}

// decode grid tables: per j, S_j f-splits of width F_j, x NTD d-tiles.
__device__ const int SJ_[6]   = {6, 12, 16, 24, 24, 32};
__device__ const int FJ_[6]   = {1024, 512, 384, 256, 256, 192};
__device__ const int BOFF_[7] = {0, 18, 54, 102, 174, 246, 342};

// out[j][n][d] = b_dec[j][d] (added by sp==0 block) + sum_{i<=j} acts[i] @ W_dec[i][j]
// PROVEN r9 structure -- do not touch.
__global__ __launch_bounds__(256, 2) void decode_k(
    const ushort* __restrict__ acts, const float* __restrict__ W_dec,
    const float* __restrict__ b_dec, float* __restrict__ out)
{
  __shared__ float lw[2][32][TD];   // 64 KB

  const int bid = blockIdx.x;
  int j = 0;
  #pragma unroll
  for (int jj = 1; jj < 6; ++jj) if (bid >= BOFF_[jj]) j = jj;
  const int r  = bid - BOFF_[j];
  const int S  = SJ_[j];
  const int F  = FJ_[j];
  const int t  = r / S;
  const int sp = r % S;
  const int fb = sp * F;
  const int ns = F / 32;            // k-steps per i
  const int nv = (j + 1) * ns;      // total virtual steps

  const int w = threadIdx.x >> 6;
  const int lane = threadIdx.x & 63;
  const int lo = lane & 15, hi = lane >> 4;

  f32x4 acc[8][4];
  #pragma unroll
  for (int mi = 0; mi < 8; ++mi)
    #pragma unroll
    for (int ni = 0; ni < 4; ++ni)
      acc[mi][ni] = f32x4{0.f, 0.f, 0.f, 0.f};

  {
    const float* W0 = W_dec + ((size_t)(0 * NL + j) * DT + fb) * DM + t * TD;
    #pragma unroll
    for (int q = 0; q < 8; ++q) {
      const int row = w * 8 + q;
      stage16(W0 + (size_t)row * DM + lane * 4, &lw[0][row][0]);
    }
  }
  __syncthreads();

  int cur = 0;
  int i = 0, s = 0;
  #pragma unroll 1
  for (int v = 0; v < nv; ++v) {
    int i2 = i, s2 = s + 1;
    if (s2 == ns) { s2 = 0; ++i2; }

    if (v + 1 < nv) {
      const float* Ws = W_dec + ((size_t)(i2 * NL + j) * DT + fb + s2 * 32) * DM + t * TD;
      #pragma unroll
      for (int q = 0; q < 8; ++q) {
        const int row = w * 8 + q;
        stage16(Ws + (size_t)row * DM + lane * 4, &lw[cur ^ 1][row][0]);
      }
    }

    const ushort* Av = acts + (size_t)i * TOK * DT + fb + s * 32;
    bf16x8 a[8];
    #pragma unroll
    for (int mi = 0; mi < 8; ++mi)
      a[mi] = *(const bf16x8*)(Av + (size_t)(mi * 16 + lo) * DT + hi * 8);

    bf16x8 bb[4];
    #pragma unroll
    for (int ni = 0; ni < 4; ++ni) {
      const int col = w * 64 + ni * 16 + lo;
      #pragma unroll
      for (int e = 0; e < 8; ++e)
        bb[ni][e] = f2bf(lw[cur][hi * 8 + e][col]);
    }

    #pragma unroll
    for (int mi = 0; mi < 8; ++mi)
      #pragma unroll
      for (int ni = 0; ni < 4; ++ni)
        acc[mi][ni] = __builtin_amdgcn_mfma_f32_16x16x32_bf16(a[mi], bb[ni], acc[mi][ni], 0, 0, 0);

    __syncthreads();
    cur ^= 1;
    i = i2; s = s2;
  }

  float* oj = out + (size_t)j * TOK * DM;
  #pragma unroll
  for (int ni = 0; ni < 4; ++ni) {
    const int d = t * TD + w * 64 + ni * 16 + lo;
    const float bias = (sp == 0) ? b_dec[j * DM + d] : 0.f;
    #pragma unroll
    for (int mi = 0; mi < 8; ++mi)
      #pragma unroll
      for (int rr = 0; rr < 4; ++rr)
        atomicAdd(oj + (size_t)(mi * 16 + hi * 4 + rr) * DM + d, acc[mi][ni][rr] + bias);
  }
}

extern "C" void kernel_launch(void* const* d_in, const int* in_sizes, int n_in,
                              void* d_out, int out_size, void* d_ws, size_t ws_size,
                              hipStream_t stream) {
  const float* x     = (const float*)d_in[0];
  const float* W_enc = (const float*)d_in[1];
  const float* b_enc = (const float*)d_in[2];
  const float* b_dec = (const float*)d_in[3];
  const float* W_dec = (const float*)d_in[4];
  float* out = (float*)d_out;
  ushort* acts = (ushort*)d_ws;                      // 6*128*6144 bf16 = 9.44 MB
  ushort* xb   = acts + (size_t)NL * TOK * DT;       // 6*128*768 bf16 = 1.18 MB

  hipMemsetAsync(out, 0, (size_t)out_size * sizeof(float), stream);
  initcvt_k<<<dim3((NL * TOK * DM + 255) / 256), dim3(256), 0, stream>>>(x, xb);
  encode_k<<<dim3(NL * (DT / EF)), dim3(256), 0, stream>>>(xb, W_enc, b_enc, acts);
  decode_k<<<dim3(342), dim3(256), 0, stream>>>(acts, W_dec, b_dec, out);
}